// Round 19
// baseline (32004.047 us; speedup 1.0000x reference)
//
#include <hip/hip_runtime.h>

#define S_LEN 4096
#define BATCH 16
#define HDIM  512
#define NSLICE 8                                   // blocks per batch
#define OUT_MAIN ((size_t)BATCH * S_LEN * HDIM)    // 33,554,432 f32 elements

// ws layout (ws >= 304MB proven by r10 pathA):
#define WS_SPK   ((size_t)0)                            // spikes u8 [S][B][H]
#define WS_IC    ((size_t)33554432)                     // ic f32 [B*S][H] (128MB)
#define WS_HTAG  (WS_IC + (size_t)134217728)            // tagged h u64 [2][B][H] (128KB)
#define WS_NEED  (WS_HTAG + (size_t)131072)

typedef unsigned long long u64;

// ---------------------------------------------------------------------------
// ic[b*S+t][j] = (sequential-d chain of fadd(fmul(x,w))) + bi[j]  — np-exact
// ---------------------------------------------------------------------------
__global__ __launch_bounds__(256, 2)
void ic_gemm(const float* __restrict__ x, const float* __restrict__ Wi,
             const float* __restrict__ bi, float* __restrict__ ic)
{
    const int r0  = blockIdx.x * 16;          // rows over B*S
    const int j0  = blockIdx.y * 64;
    const int tid = threadIdx.x;
    const int jj  = tid & 63, ts = tid >> 6;

    __shared__ float xs[16][512];
#pragma unroll
    for (int kr = 0; kr < 32; ++kr) {
        int i = tid + 256 * kr;
        xs[i >> 9][i & 511] = x[(size_t)r0 * HDIM + i];
    }
    __syncthreads();

    float a0 = 0.f, a1 = 0.f, a2 = 0.f, a3 = 0.f;
    const float* wj = Wi + j0 + jj;
#pragma unroll 8
    for (int d = 0; d < HDIM; ++d) {
        const float w = wj[(size_t)d * HDIM];
        a0 = __fadd_rn(a0, __fmul_rn(xs[ts * 4 + 0][d], w));
        a1 = __fadd_rn(a1, __fmul_rn(xs[ts * 4 + 1][d], w));
        a2 = __fadd_rn(a2, __fmul_rn(xs[ts * 4 + 2][d], w));
        a3 = __fadd_rn(a3, __fmul_rn(xs[ts * 4 + 3][d], w));
    }
    const float bv = bi[j0 + jj];
    ic[(size_t)(r0 + ts * 4 + 0) * HDIM + j0 + jj] = __fadd_rn(a0, bv);
    ic[(size_t)(r0 + ts * 4 + 1) * HDIM + j0 + jj] = __fadd_rn(a1, bv);
    ic[(size_t)(r0 + ts * 4 + 2) * HDIM + j0 + jj] = __fadd_rn(a2, bv);
    ic[(size_t)(r0 + ts * 4 + 3) * HDIM + j0 + jj] = __fadd_rn(a3, bv);
}

// ---------------------------------------------------------------------------
// Scan: 8 blocks/batch, 64 channels each, full Wh slice in LDS.
// Exchange = tagged dataflow (signal+data in one relaxed 8B agent atomic).
// RACE FIX vs r18: __syncthreads() between produce phase and poll phase —
// waves 1-3 must not overwrite h_lds while wave 0's chain still reads it.
// ---------------------------------------------------------------------------
__global__ __launch_bounds__(256, 1)
void scan_tag(const float* __restrict__ Wh, const float* __restrict__ bh,
              const float* __restrict__ ic, unsigned char* __restrict__ spk,
              u64* __restrict__ htag, float* __restrict__ out)
{
    const int tid = threadIdx.x;
    const int b   = blockIdx.x & 15;      // batch
    const int sl  = blockIdx.x >> 4;      // slice 0..7
    const int c0  = sl * 64;

    __shared__ float wh_lds[64 * 516];    // [ci][k], row stride 516
    __shared__ float h_lds[512];

    for (int i = tid; i < 64 * 512; i += 256) {
        const int k = i >> 6, ci = i & 63;
        wh_lds[ci * 516 + k] = Wh[(size_t)k * HDIM + c0 + ci];
    }
    float rbh = 0.f, v = 0.f, hn = 0.f, sp = 0.f;
    if (tid < 64) rbh = bh[c0 + tid];
    h_lds[tid] = 0.f; h_lds[tid + 256] = 0.f;
    __syncthreads();

    const float* icb = ic + (size_t)b * S_LEN * HDIM + c0;

    for (int t = 0; t < S_LEN; ++t) {
        if (tid < 64) {
            const float icv = icb[(size_t)t * HDIM + tid];   // early load

            // np-exact sequential-k FMA chain (k = 0..511 in order)
            const float* wrow = &wh_lds[tid * 516];
            float ah = 0.f;
#pragma unroll 32
            for (int k4 = 0; k4 < 128; ++k4) {
                const float4 wv = *(const float4*)(wrow + 4 * k4);
                const float4 hv = *(const float4*)(&h_lds[4 * k4]);
                ah = __fmaf_rn(hv.x, wv.x, ah);
                ah = __fmaf_rn(hv.y, wv.y, ah);
                ah = __fmaf_rn(hv.z, wv.z, ah);
                ah = __fmaf_rn(hv.w, wv.w, ah);
            }
            const float hc = __fadd_rn(ah, rbh);     // (h@Wh) + bh
            const float ho = h_lds[c0 + tid];
            const float t1 = __fadd_rn(-ho, icv);    // -h + ic
            const float t2 = __fadd_rn(t1, hc);      // ... + hc
            const float t3 = __fmul_rn(t2, 0.1f);    // * inv_tau
            hn = __fadd_rn(ho, t3);                  // h_new
            const float u1 = __fadd_rn(-v, hn);
            const float u2 = __fmul_rn(u1, 0.1f);
            const float vn = __fadd_rn(v, u2);
            sp = (vn >= 1.0f) ? 1.0f : 0.0f;
            v  = (vn >= 1.0f) ? 0.0f : vn;

            spk[((size_t)t * BATCH + b) * HDIM + c0 + tid] = (unsigned char)sp;

            // signal+data in ONE 8B word: tag (t+1) << 32 | f32 bits
            union { float f; unsigned int u; } cv; cv.f = hn;
            const u64 w = ((u64)(unsigned int)(t + 1) << 32) | (u64)cv.u;
            __hip_atomic_store(&htag[(size_t)((t + 1) & 1) * (BATCH * HDIM) + b * HDIM + c0 + tid],
                               w, __ATOMIC_RELAXED, __HIP_MEMORY_SCOPE_AGENT);
        }

        // RACE FIX: chain (wave 0) must finish reading h_lds before any wave
        // starts overwriting it with next-step values.
        __syncthreads();

        // poll phase: all 256 threads gather 2 channels each for next step
        {
            const u64* src = htag + (size_t)((t + 1) & 1) * (BATCH * HDIM) + b * HDIM;
            const unsigned int want = (unsigned int)(t + 1);
            float r0f = 0.f, r1f = 0.f;
            bool d0 = false, d1 = false;
            long spin = 0;
            while (!(d0 && d1)) {
                if (!d0) {
                    const u64 w = __hip_atomic_load(&src[tid], __ATOMIC_RELAXED, __HIP_MEMORY_SCOPE_AGENT);
                    if ((unsigned int)(w >> 32) == want) {
                        union { unsigned int u; float f; } cv; cv.u = (unsigned int)w; r0f = cv.f; d0 = true;
                    }
                }
                if (!d1) {
                    const u64 w = __hip_atomic_load(&src[tid + 256], __ATOMIC_RELAXED, __HIP_MEMORY_SCOPE_AGENT);
                    if ((unsigned int)(w >> 32) == want) {
                        union { unsigned int u; float f; } cv; cv.u = (unsigned int)w; r1f = cv.f; d1 = true;
                    }
                }
                if (++spin > 100000000L) break;                 // fail loud, never hang
                if (spin > 4) __builtin_amdgcn_s_sleep(1);      // back off only when waiting
            }
            h_lds[tid]       = r0f;
            h_lds[tid + 256] = r1f;
        }
        __syncthreads();   // h_lds complete for next chain
    }

    if (tid < 64) {
        out[OUT_MAIN + (size_t)b * HDIM + c0 + tid]          = hn;   // h_f
        out[OUT_MAIN + 8192 + (size_t)b * HDIM + c0 + tid]   = v;    // v_f
        out[OUT_MAIN + 16384 + (size_t)b * HDIM + c0 + tid]  = sp;   // spikes_last
    }
}

// ---------------------------------------------------------------------------
// Fallback single-block fused scan (r14, proven) if ws is too small.
// ---------------------------------------------------------------------------
__global__ __launch_bounds__(512, 2)
void scan_f32(const float* __restrict__ x, const float* __restrict__ Wi,
              const float* __restrict__ bi, const float* __restrict__ Wh,
              const float* __restrict__ bh, unsigned char* __restrict__ spk,
              float* __restrict__ out)
{
    const int b = blockIdx.x;
    const int j = threadIdx.x;
    __shared__ float h_lds[HDIM];
    __shared__ float x_lds[HDIM];
    float v = 0.0f, hn = 0.0f, sp = 0.0f;
    const float rbh = bh[j], rbi = bi[j];
    h_lds[j] = 0.0f;
    const float* xb = x + (size_t)b * S_LEN * HDIM;
    for (int t = 0; t < S_LEN; ++t) {
        x_lds[j] = xb[(size_t)t * HDIM + j];
        __syncthreads();
        float ah = 0.0f, ax = 0.0f;
        const float* wj = Wh + j;
        const float* qj = Wi + j;
#pragma unroll 8
        for (int k = 0; k < HDIM; ++k) {
            ah = __fmaf_rn(h_lds[k], wj[(size_t)k * HDIM], ah);
            ax = __fadd_rn(ax, __fmul_rn(x_lds[k], qj[(size_t)k * HDIM]));
        }
        const float hc = __fadd_rn(ah, rbh);
        const float icv = __fadd_rn(ax, rbi);
        const float ho = h_lds[j];
        const float t1 = __fadd_rn(-ho, icv);
        const float t2 = __fadd_rn(t1, hc);
        const float t3 = __fmul_rn(t2, 0.1f);
        hn = __fadd_rn(ho, t3);
        const float u1 = __fadd_rn(-v, hn);
        const float u2 = __fmul_rn(u1, 0.1f);
        const float vn = __fadd_rn(v, u2);
        sp = (vn >= 1.0f) ? 1.0f : 0.0f;
        v  = (vn >= 1.0f) ? 0.0f : vn;
        spk[((size_t)t * BATCH + b) * HDIM + j] = (unsigned char)sp;
        __syncthreads();
        h_lds[j] = hn;
        __syncthreads();
    }
    out[OUT_MAIN + (size_t)b * HDIM + j]          = hn;
    out[OUT_MAIN + 8192 + (size_t)b * HDIM + j]   = v;
    out[OUT_MAIN + 16384 + (size_t)b * HDIM + j]  = sp;
}

// ---------------------------------------------------------------------------
// outputs[b,s,d] = sum_h spikes[s,b,h] * Wo[h*512+d] + bo[d]
// ---------------------------------------------------------------------------
__global__ __launch_bounds__(256, 2)
void out_gemm(const unsigned char* __restrict__ spikes, const float* __restrict__ Wo,
              const float* __restrict__ bo, float* __restrict__ out)
{
    const int s0 = blockIdx.x * 64;
    const int d0 = blockIdx.y * 64;
    const int b  = blockIdx.z;
    const int tid = threadIdx.x;

    __shared__ float sA[32][68];
    __shared__ float sB[32][68];

    float acc[4][4] = {};
    const int tm = tid >> 4, tn = tid & 15;
    const int m0 = tm * 4, n0 = tn * 4;

    for (int k0 = 0; k0 < HDIM; k0 += 32) {
        {
            const int m = tid >> 2, kq = (tid & 3) * 8;
            const unsigned char* pp = spikes + ((size_t)(s0 + m) * BATCH + b) * HDIM + k0 + kq;
            uchar4 u0 = *(const uchar4*)pp;
            uchar4 u1 = *(const uchar4*)(pp + 4);
            sA[kq+0][m] = (float)u0.x; sA[kq+1][m] = (float)u0.y;
            sA[kq+2][m] = (float)u0.z; sA[kq+3][m] = (float)u0.w;
            sA[kq+4][m] = (float)u1.x; sA[kq+5][m] = (float)u1.y;
            sA[kq+6][m] = (float)u1.z; sA[kq+7][m] = (float)u1.w;
        }
        {
            const int k = tid >> 3, n8 = (tid & 7) * 8;
            const float* pw = Wo + (size_t)(k0 + k) * HDIM + d0 + n8;
            float4 v0 = *(const float4*)pw;
            float4 v1 = *(const float4*)(pw + 4);
            *(float4*)&sB[k][n8]     = v0;
            *(float4*)&sB[k][n8 + 4] = v1;
        }
        __syncthreads();
#pragma unroll
        for (int k = 0; k < 32; ++k) {
            float a0 = sA[k][m0+0], a1 = sA[k][m0+1], a2 = sA[k][m0+2], a3 = sA[k][m0+3];
            float b0v = sB[k][n0+0], b1v = sB[k][n0+1], b2v = sB[k][n0+2], b3v = sB[k][n0+3];
            acc[0][0] += a0*b0v; acc[0][1] += a0*b1v; acc[0][2] += a0*b2v; acc[0][3] += a0*b3v;
            acc[1][0] += a1*b0v; acc[1][1] += a1*b1v; acc[1][2] += a1*b2v; acc[1][3] += a1*b3v;
            acc[2][0] += a2*b0v; acc[2][1] += a2*b1v; acc[2][2] += a2*b2v; acc[2][3] += a2*b3v;
            acc[3][0] += a3*b0v; acc[3][1] += a3*b1v; acc[3][2] += a3*b2v; acc[3][3] += a3*b3v;
        }
        __syncthreads();
    }

    float bov[4];
#pragma unroll
    for (int j = 0; j < 4; ++j) bov[j] = bo[d0 + n0 + j];
#pragma unroll
    for (int i = 0; i < 4; ++i) {
        size_t row = (size_t)b * S_LEN + s0 + m0 + i;
        float* o = out + row * HDIM + d0 + n0;
#pragma unroll
        for (int j = 0; j < 4; ++j)
            o[j] = acc[i][j] + bov[j];
    }
}

extern "C" void kernel_launch(void* const* d_in, const int* in_sizes, int n_in,
                              void* d_out, int out_size, void* d_ws, size_t ws_size,
                              hipStream_t stream)
{
    const float* x  = (const float*)d_in[0];
    const float* Wi = (const float*)d_in[1];
    const float* bi = (const float*)d_in[2];
    const float* Wh = (const float*)d_in[3];
    const float* bh = (const float*)d_in[4];
    const float* Wo = (const float*)d_in[5];
    const float* bo = (const float*)d_in[6];
    float* out = (float*)d_out;

    unsigned char* spikes = (unsigned char*)d_ws + WS_SPK;
    float*         ic     = (float*)((char*)d_ws + WS_IC);
    u64*           htag   = (u64*)((char*)d_ws + WS_HTAG);

    if (ws_size >= WS_NEED) {
        // clear stale tags from prior replay (tags 1..4096 would alias)
        hipMemsetAsync((char*)d_ws + WS_HTAG, 0, 131072, stream);
        ic_gemm<<<dim3((BATCH * S_LEN) / 16, HDIM / 64), dim3(256), 0, stream>>>(x, Wi, bi, ic);
        scan_tag<<<dim3(BATCH * NSLICE), dim3(256), 0, stream>>>(Wh, bh, ic, spikes, htag, out);
    } else {
        scan_f32<<<dim3(BATCH), dim3(512), 0, stream>>>(x, Wi, bi, Wh, bh, spikes, out);
    }

    out_gemm<<<dim3(S_LEN / 64, HDIM / 64, BATCH), dim3(256), 0, stream>>>(spikes, Wo, bo, out);
}

// Round 20
// 23094.209 us; speedup vs baseline: 1.3858x; 1.3858x over previous
//
#include <hip/hip_runtime.h>

#define S_LEN 4096
#define BATCH 16
#define HDIM  512
#define NSLICE 8                                   // blocks per batch
#define OUT_MAIN ((size_t)BATCH * S_LEN * HDIM)    // 33,554,432 f32 elements

// ws layout (ws >= 304MB proven by r10 pathA):
#define WS_SPK   ((size_t)0)                            // spikes u8 [S][B][H]
#define WS_IC    ((size_t)33554432)                     // ic f32 [B*S][H] (128MB)
#define WS_HTAG  (WS_IC + (size_t)134217728)            // tagged h u64 [2][B][H] (128KB)
#define WS_NEED  (WS_HTAG + (size_t)131072)

typedef unsigned long long u64;

// ---------------------------------------------------------------------------
// ic[b*S+t][j] = (sequential-d chain of fadd(fmul(x,w))) + bi[j]  — np-exact
// ---------------------------------------------------------------------------
__global__ __launch_bounds__(256, 2)
void ic_gemm(const float* __restrict__ x, const float* __restrict__ Wi,
             const float* __restrict__ bi, float* __restrict__ ic)
{
    const int r0  = blockIdx.x * 16;          // rows over B*S
    const int j0  = blockIdx.y * 64;
    const int tid = threadIdx.x;
    const int jj  = tid & 63, ts = tid >> 6;

    __shared__ float xs[16][512];
#pragma unroll
    for (int kr = 0; kr < 32; ++kr) {
        int i = tid + 256 * kr;
        xs[i >> 9][i & 511] = x[(size_t)r0 * HDIM + i];
    }
    __syncthreads();

    float a0 = 0.f, a1 = 0.f, a2 = 0.f, a3 = 0.f;
    const float* wj = Wi + j0 + jj;
#pragma unroll 8
    for (int d = 0; d < HDIM; ++d) {
        const float w = wj[(size_t)d * HDIM];
        a0 = __fadd_rn(a0, __fmul_rn(xs[ts * 4 + 0][d], w));
        a1 = __fadd_rn(a1, __fmul_rn(xs[ts * 4 + 1][d], w));
        a2 = __fadd_rn(a2, __fmul_rn(xs[ts * 4 + 2][d], w));
        a3 = __fadd_rn(a3, __fmul_rn(xs[ts * 4 + 3][d], w));
    }
    const float bv = bi[j0 + jj];
    ic[(size_t)(r0 + ts * 4 + 0) * HDIM + j0 + jj] = __fadd_rn(a0, bv);
    ic[(size_t)(r0 + ts * 4 + 1) * HDIM + j0 + jj] = __fadd_rn(a1, bv);
    ic[(size_t)(r0 + ts * 4 + 2) * HDIM + j0 + jj] = __fadd_rn(a2, bv);
    ic[(size_t)(r0 + ts * 4 + 3) * HDIM + j0 + jj] = __fadd_rn(a3, bv);
}

// ---------------------------------------------------------------------------
// Scan: 8 blocks/batch, 64 channels each, full Wh slice in LDS.
// Tagged-dataflow exchange (signal+data in one relaxed 8B agent atomic).
// r20 changes: (1) wave0 self-supplies its own channels to LDS (no self-poll),
// (2) threads 0..223 poll only the 448 REMOTE channels, (3) tight spin
// (s_sleep only as >16k-miss deadlock backoff).
// ---------------------------------------------------------------------------
__global__ __launch_bounds__(256, 1)
void scan_tag(const float* __restrict__ Wh, const float* __restrict__ bh,
              const float* __restrict__ ic, unsigned char* __restrict__ spk,
              u64* __restrict__ htag, float* __restrict__ out)
{
    const int tid = threadIdx.x;
    const int b   = blockIdx.x & 15;      // batch
    const int sl  = blockIdx.x >> 4;      // slice 0..7
    const int c0  = sl * 64;

    __shared__ float wh_lds[64 * 516];    // [ci][k], row stride 516
    __shared__ float h_lds[512];

    for (int i = tid; i < 64 * 512; i += 256) {
        const int k = i >> 6, ci = i & 63;
        wh_lds[ci * 516 + k] = Wh[(size_t)k * HDIM + c0 + ci];
    }
    float rbh = 0.f, v = 0.f, hn = 0.f, sp = 0.f;
    if (tid < 64) rbh = bh[c0 + tid];
    h_lds[tid] = 0.f; h_lds[tid + 256] = 0.f;
    __syncthreads();

    const float* icb = ic + (size_t)b * S_LEN * HDIM + c0;

    // remote-channel mapping for pollers: 448 channels excluding [c0, c0+64)
    const int i0 = 2 * tid, i1 = 2 * tid + 1;
    const int ch0 = (i0 >= c0) ? i0 + 64 : i0;
    const int ch1 = (i1 >= c0) ? i1 + 64 : i1;

    for (int t = 0; t < S_LEN; ++t) {
        if (tid < 64) {
            const float icv = icb[(size_t)t * HDIM + tid];   // early load

            // np-exact sequential-k FMA chain (k = 0..511 in order)
            const float* wrow = &wh_lds[tid * 516];
            float ah = 0.f;
#pragma unroll 32
            for (int k4 = 0; k4 < 128; ++k4) {
                const float4 wv = *(const float4*)(wrow + 4 * k4);
                const float4 hv = *(const float4*)(&h_lds[4 * k4]);
                ah = __fmaf_rn(hv.x, wv.x, ah);
                ah = __fmaf_rn(hv.y, wv.y, ah);
                ah = __fmaf_rn(hv.z, wv.z, ah);
                ah = __fmaf_rn(hv.w, wv.w, ah);
            }
            const float hc = __fadd_rn(ah, rbh);     // (h@Wh) + bh
            const float ho = h_lds[c0 + tid];
            const float t1 = __fadd_rn(-ho, icv);    // -h + ic
            const float t2 = __fadd_rn(t1, hc);      // ... + hc
            const float t3 = __fmul_rn(t2, 0.1f);    // * inv_tau
            hn = __fadd_rn(ho, t3);                  // h_new
            const float u1 = __fadd_rn(-v, hn);
            const float u2 = __fmul_rn(u1, 0.1f);
            const float vn = __fadd_rn(v, u2);
            sp = (vn >= 1.0f) ? 1.0f : 0.0f;
            v  = (vn >= 1.0f) ? 0.0f : vn;

            spk[((size_t)t * BATCH + b) * HDIM + c0 + tid] = (unsigned char)sp;

            // publish for other blocks: tag (t+1) << 32 | f32 bits, one 8B word
            union { float f; unsigned int u; } cv; cv.f = hn;
            const u64 w = ((u64)(unsigned int)(t + 1) << 32) | (u64)cv.u;
            __hip_atomic_store(&htag[(size_t)((t + 1) & 1) * (BATCH * HDIM) + b * HDIM + c0 + tid],
                               w, __ATOMIC_RELAXED, __HIP_MEMORY_SCOPE_AGENT);

            // self-supply own channel (wave-lockstep: all chain reads complete)
            h_lds[c0 + tid] = hn;
        }

        // chain must finish reading h_lds before pollers overwrite it (r18 race fix)
        __syncthreads();

        // poll phase: threads 0..223 gather the 448 remote channels (2 each)
        if (tid < 224) {
            const u64* src = htag + (size_t)((t + 1) & 1) * (BATCH * HDIM) + b * HDIM;
            const unsigned int want = (unsigned int)(t + 1);
            float r0f = 0.f, r1f = 0.f;
            bool d0 = false, d1 = false;
            long spin = 0;
            while (!(d0 && d1)) {
                if (!d0) {
                    const u64 w = __hip_atomic_load(&src[ch0], __ATOMIC_RELAXED, __HIP_MEMORY_SCOPE_AGENT);
                    if ((unsigned int)(w >> 32) == want) {
                        union { unsigned int u; float f; } cv; cv.u = (unsigned int)w; r0f = cv.f; d0 = true;
                    }
                }
                if (!d1) {
                    const u64 w = __hip_atomic_load(&src[ch1], __ATOMIC_RELAXED, __HIP_MEMORY_SCOPE_AGENT);
                    if ((unsigned int)(w >> 32) == want) {
                        union { unsigned int u; float f; } cv; cv.u = (unsigned int)w; r1f = cv.f; d1 = true;
                    }
                }
                ++spin;
                if (spin > 200000000L) break;                    // fail loud, never hang
                if (spin > 16384) __builtin_amdgcn_s_sleep(1);   // deadlock backoff only
            }
            h_lds[ch0] = r0f;
            h_lds[ch1] = r1f;
        }
        __syncthreads();   // h_lds complete for next chain
    }

    if (tid < 64) {
        out[OUT_MAIN + (size_t)b * HDIM + c0 + tid]          = hn;   // h_f
        out[OUT_MAIN + 8192 + (size_t)b * HDIM + c0 + tid]   = v;    // v_f
        out[OUT_MAIN + 16384 + (size_t)b * HDIM + c0 + tid]  = sp;   // spikes_last
    }
}

// ---------------------------------------------------------------------------
// Fallback single-block fused scan (r14, proven) if ws is too small.
// ---------------------------------------------------------------------------
__global__ __launch_bounds__(512, 2)
void scan_f32(const float* __restrict__ x, const float* __restrict__ Wi,
              const float* __restrict__ bi, const float* __restrict__ Wh,
              const float* __restrict__ bh, unsigned char* __restrict__ spk,
              float* __restrict__ out)
{
    const int b = blockIdx.x;
    const int j = threadIdx.x;
    __shared__ float h_lds[HDIM];
    __shared__ float x_lds[HDIM];
    float v = 0.0f, hn = 0.0f, sp = 0.0f;
    const float rbh = bh[j], rbi = bi[j];
    h_lds[j] = 0.0f;
    const float* xb = x + (size_t)b * S_LEN * HDIM;
    for (int t = 0; t < S_LEN; ++t) {
        x_lds[j] = xb[(size_t)t * HDIM + j];
        __syncthreads();
        float ah = 0.0f, ax = 0.0f;
        const float* wj = Wh + j;
        const float* qj = Wi + j;
#pragma unroll 8
        for (int k = 0; k < HDIM; ++k) {
            ah = __fmaf_rn(h_lds[k], wj[(size_t)k * HDIM], ah);
            ax = __fadd_rn(ax, __fmul_rn(x_lds[k], qj[(size_t)k * HDIM]));
        }
        const float hc = __fadd_rn(ah, rbh);
        const float icv = __fadd_rn(ax, rbi);
        const float ho = h_lds[j];
        const float t1 = __fadd_rn(-ho, icv);
        const float t2 = __fadd_rn(t1, hc);
        const float t3 = __fmul_rn(t2, 0.1f);
        hn = __fadd_rn(ho, t3);
        const float u1 = __fadd_rn(-v, hn);
        const float u2 = __fmul_rn(u1, 0.1f);
        const float vn = __fadd_rn(v, u2);
        sp = (vn >= 1.0f) ? 1.0f : 0.0f;
        v  = (vn >= 1.0f) ? 0.0f : vn;
        spk[((size_t)t * BATCH + b) * HDIM + j] = (unsigned char)sp;
        __syncthreads();
        h_lds[j] = hn;
        __syncthreads();
    }
    out[OUT_MAIN + (size_t)b * HDIM + j]          = hn;
    out[OUT_MAIN + 8192 + (size_t)b * HDIM + j]   = v;
    out[OUT_MAIN + 16384 + (size_t)b * HDIM + j]  = sp;
}

// ---------------------------------------------------------------------------
// outputs[b,s,d] = sum_h spikes[s,b,h] * Wo[h*512+d] + bo[d]
// ---------------------------------------------------------------------------
__global__ __launch_bounds__(256, 2)
void out_gemm(const unsigned char* __restrict__ spikes, const float* __restrict__ Wo,
              const float* __restrict__ bo, float* __restrict__ out)
{
    const int s0 = blockIdx.x * 64;
    const int d0 = blockIdx.y * 64;
    const int b  = blockIdx.z;
    const int tid = threadIdx.x;

    __shared__ float sA[32][68];
    __shared__ float sB[32][68];

    float acc[4][4] = {};
    const int tm = tid >> 4, tn = tid & 15;
    const int m0 = tm * 4, n0 = tn * 4;

    for (int k0 = 0; k0 < HDIM; k0 += 32) {
        {
            const int m = tid >> 2, kq = (tid & 3) * 8;
            const unsigned char* pp = spikes + ((size_t)(s0 + m) * BATCH + b) * HDIM + k0 + kq;
            uchar4 u0 = *(const uchar4*)pp;
            uchar4 u1 = *(const uchar4*)(pp + 4);
            sA[kq+0][m] = (float)u0.x; sA[kq+1][m] = (float)u0.y;
            sA[kq+2][m] = (float)u0.z; sA[kq+3][m] = (float)u0.w;
            sA[kq+4][m] = (float)u1.x; sA[kq+5][m] = (float)u1.y;
            sA[kq+6][m] = (float)u1.z; sA[kq+7][m] = (float)u1.w;
        }
        {
            const int k = tid >> 3, n8 = (tid & 7) * 8;
            const float* pw = Wo + (size_t)(k0 + k) * HDIM + d0 + n8;
            float4 v0 = *(const float4*)pw;
            float4 v1 = *(const float4*)(pw + 4);
            *(float4*)&sB[k][n8]     = v0;
            *(float4*)&sB[k][n8 + 4] = v1;
        }
        __syncthreads();
#pragma unroll
        for (int k = 0; k < 32; ++k) {
            float a0 = sA[k][m0+0], a1 = sA[k][m0+1], a2 = sA[k][m0+2], a3 = sA[k][m0+3];
            float b0v = sB[k][n0+0], b1v = sB[k][n0+1], b2v = sB[k][n0+2], b3v = sB[k][n0+3];
            acc[0][0] += a0*b0v; acc[0][1] += a0*b1v; acc[0][2] += a0*b2v; acc[0][3] += a0*b3v;
            acc[1][0] += a1*b0v; acc[1][1] += a1*b1v; acc[1][2] += a1*b2v; acc[1][3] += a1*b3v;
            acc[2][0] += a2*b0v; acc[2][1] += a2*b1v; acc[2][2] += a2*b2v; acc[2][3] += a2*b3v;
            acc[3][0] += a3*b0v; acc[3][1] += a3*b1v; acc[3][2] += a3*b2v; acc[3][3] += a3*b3v;
        }
        __syncthreads();
    }

    float bov[4];
#pragma unroll
    for (int j = 0; j < 4; ++j) bov[j] = bo[d0 + n0 + j];
#pragma unroll
    for (int i = 0; i < 4; ++i) {
        size_t row = (size_t)b * S_LEN + s0 + m0 + i;
        float* o = out + row * HDIM + d0 + n0;
#pragma unroll
        for (int j = 0; j < 4; ++j)
            o[j] = acc[i][j] + bov[j];
    }
}

extern "C" void kernel_launch(void* const* d_in, const int* in_sizes, int n_in,
                              void* d_out, int out_size, void* d_ws, size_t ws_size,
                              hipStream_t stream)
{
    const float* x  = (const float*)d_in[0];
    const float* Wi = (const float*)d_in[1];
    const float* bi = (const float*)d_in[2];
    const float* Wh = (const float*)d_in[3];
    const float* bh = (const float*)d_in[4];
    const float* Wo = (const float*)d_in[5];
    const float* bo = (const float*)d_in[6];
    float* out = (float*)d_out;

    unsigned char* spikes = (unsigned char*)d_ws + WS_SPK;
    float*         ic     = (float*)((char*)d_ws + WS_IC);
    u64*           htag   = (u64*)((char*)d_ws + WS_HTAG);

    if (ws_size >= WS_NEED) {
        // clear stale tags from prior replay (tags 1..4096 would alias)
        hipMemsetAsync((char*)d_ws + WS_HTAG, 0, 131072, stream);
        ic_gemm<<<dim3((BATCH * S_LEN) / 16, HDIM / 64), dim3(256), 0, stream>>>(x, Wi, bi, ic);
        scan_tag<<<dim3(BATCH * NSLICE), dim3(256), 0, stream>>>(Wh, bh, ic, spikes, htag, out);
    } else {
        scan_f32<<<dim3(BATCH), dim3(512), 0, stream>>>(x, Wi, bi, Wh, bh, spikes, out);
    }

    out_gemm<<<dim3(S_LEN / 64, HDIM / 64, BATCH), dim3(256), 0, stream>>>(spikes, Wo, bo, out);
}